// Round 8
// baseline (289.583 us; speedup 1.0000x reference)
//
#include <hip/hip_runtime.h>
#include <math.h>

#define N_TOTAL 40960
#define M_EV    4096
#define KNN     32
#define FEAT    192   // CIN + 2*PDIM

__device__ __forceinline__ float dot4f(float4 a, float4 b) {
    return fmaf(a.w, b.w, fmaf(a.z, b.z, fmaf(a.y, b.y, a.x * b.x)));
}

// ---------------------------------------------------------------------------
// Kernel 1: space = x@W_space + b_space  [N,4];  prop = x@W_prop + b_prop [N,64]
// ---------------------------------------------------------------------------
__global__ __launch_bounds__(256) void k_linear(
    const float* __restrict__ x,
    const float* __restrict__ Wp, const float* __restrict__ bp,
    const float* __restrict__ Ws, const float* __restrict__ bs,
    float* __restrict__ prop, float* __restrict__ space)
{
    __shared__ float xs[16 * 64];
    const int t = threadIdx.x;
    const int rowbase = blockIdx.x * 16;

    {
        float4 v = *(const float4*)(x + rowbase * 64 + t * 4);
        *(float4*)(xs + t * 4) = v;
    }
    __syncthreads();

    const int j  = t & 63;
    const int rg = t >> 6;
    float a0 = 0.f, a1 = 0.f, a2 = 0.f, a3 = 0.f;
#pragma unroll 8
    for (int c = 0; c < 64; ++c) {
        float w = Wp[c * 64 + j];
        a0 = fmaf(xs[(rg * 4 + 0) * 64 + c], w, a0);
        a1 = fmaf(xs[(rg * 4 + 1) * 64 + c], w, a1);
        a2 = fmaf(xs[(rg * 4 + 2) * 64 + c], w, a2);
        a3 = fmaf(xs[(rg * 4 + 3) * 64 + c], w, a3);
    }
    const float bj = bp[j];
    prop[(rowbase + rg * 4 + 0) * 64 + j] = a0 + bj;
    prop[(rowbase + rg * 4 + 1) * 64 + j] = a1 + bj;
    prop[(rowbase + rg * 4 + 2) * 64 + j] = a2 + bj;
    prop[(rowbase + rg * 4 + 3) * 64 + j] = a3 + bj;

    if (t < 64) {
        const int r = t >> 2, s = t & 3;
        float a = 0.f;
#pragma unroll 8
        for (int c = 0; c < 64; ++c)
            a = fmaf(xs[r * 64 + c], Ws[c * 4 + s], a);
        space[(rowbase + r) * 4 + s] = a + bs[s];
    }
}

// ---------------------------------------------------------------------------
// Kernel 2: exact kNN, threshold-compact-sort, 8 queries/wave.
// Ranking key: dh = |c|^2/2 - q.c  (monotone with d^2 = 2*dh + |q|^2; true d
// only recovered at the 32 outputs). Pass1 and pass2 use the identical fma
// chain => bitwise-consistent with threshold T = 32nd-smallest lane minimum.
// Guarantee: >=32 distinct candidates have dh<=T  =>  top-32 in {dh<=T}.
// ---------------------------------------------------------------------------
#define QPW   8
#define QPB   32
#define TILEC 512
#define CCAP  128

__global__ __launch_bounds__(256, 1) void k_knn(
    const float4* __restrict__ space4,
    int* __restrict__ knn_idx, float* __restrict__ knn_w,
    int* __restrict__ bad)
{
    __shared__ float4 s_c[TILEC];         //  8192 B
    __shared__ float  s_h[TILEC];         //  2048 B  (half |c|^2)
    __shared__ float  s_cd[QPB * CCAP];   // 16384 B
    __shared__ ushort s_ci[QPB * CCAP];   //  8192 B
    __shared__ int    s_cnt[QPB];         //   128 B  => 34944 B, 4 blocks/CU

    const int t = threadIdx.x;
    const int w = t >> 6;
    const int l = t & 63;
    const int qb = blockIdx.x * QPB;
    const int ebase = (qb / M_EV) * M_EV;

    if (t < QPB) s_cnt[t] = 0;           // wave 0; covered by first barrier

    float4 qcs[QPW]; float sqq[QPW];
#pragma unroll
    for (int s = 0; s < QPW; ++s) {
        qcs[s] = space4[qb + w * QPW + s];
        sqq[s] = dot4f(qcs[s], qcs[s]);
    }

    float mn[QPW];
#pragma unroll
    for (int s = 0; s < QPW; ++s) mn[s] = INFINITY;

    // ---- pass 1: per-lane slice minima of dh ----
#pragma unroll 1
    for (int tile = 0; tile < M_EV / TILEC; ++tile) {
        __syncthreads();
#pragma unroll
        for (int u = 0; u < TILEC / 256; ++u) {
            int ci = u * 256 + t;
            float4 c = space4[ebase + tile * TILEC + ci];
            s_c[ci] = c;
            s_h[ci] = 0.5f * dot4f(c, c);
        }
        __syncthreads();
#pragma unroll 2
        for (int j = 0; j < TILEC / 64; ++j) {
            int ci = j * 64 + l;
            float4 c = s_c[ci]; float hc = s_h[ci];
#pragma unroll
            for (int s = 0; s < QPW; ++s) {
                float dh = fmaf(-qcs[s].x, c.x, hc);
                dh = fmaf(-qcs[s].y, c.y, dh);
                dh = fmaf(-qcs[s].z, c.z, dh);
                dh = fmaf(-qcs[s].w, c.w, dh);
                mn[s] = fminf(mn[s], dh);
            }
        }
    }

    // ---- T[s] = 32nd smallest of the 64 lane minima (8 sorts in parallel) ----
    float v[QPW];
#pragma unroll
    for (int s = 0; s < QPW; ++s) v[s] = mn[s];
#pragma unroll
    for (int k = 2; k <= 64; k <<= 1) {
#pragma unroll
        for (int j = k >> 1; j >= 1; j >>= 1) {
            bool tmn = (((l & k) == 0) == ((l & j) == 0));
#pragma unroll
            for (int s = 0; s < QPW; ++s) {
                float p = __shfl_xor(v[s], j, 64);
                v[s] = tmn ? fminf(v[s], p) : fmaxf(v[s], p);
            }
        }
    }
    float T[QPW];
#pragma unroll
    for (int s = 0; s < QPW; ++s) T[s] = __shfl(v[s], 31, 64);

    // ---- pass 2: compact dh<=T (identical fma chain => bitwise equal) ----
#pragma unroll 1
    for (int tile = 0; tile < M_EV / TILEC; ++tile) {
        __syncthreads();
#pragma unroll
        for (int u = 0; u < TILEC / 256; ++u) {
            int ci = u * 256 + t;
            float4 c = space4[ebase + tile * TILEC + ci];
            s_c[ci] = c;
            s_h[ci] = 0.5f * dot4f(c, c);
        }
        __syncthreads();
#pragma unroll 2
        for (int j = 0; j < TILEC / 64; ++j) {
            int ci = j * 64 + l;
            float4 c = s_c[ci]; float hc = s_h[ci];
#pragma unroll
            for (int s = 0; s < QPW; ++s) {
                float dh = fmaf(-qcs[s].x, c.x, hc);
                dh = fmaf(-qcs[s].y, c.y, dh);
                dh = fmaf(-qcs[s].z, c.z, dh);
                dh = fmaf(-qcs[s].w, c.w, dh);
                if (dh <= T[s]) {
                    int p = atomicAdd(&s_cnt[w * QPW + s], 1);
                    if (p < CCAP) {
                        s_cd[(w * QPW + s) * CCAP + p] = dh;
                        s_ci[(w * QPW + s) * CCAP + p] = (ushort)(tile * TILEC + ci);
                    }
                }
            }
        }
    }
    // own wave wrote its own compact region; DS ops in-order per wave.

    // ---- exact select per query (set selection; mean/max are order-free) ----
#pragma unroll 1
    for (int s = 0; s < QPW; ++s) {
        const int qi = w * QPW + s;
        const int q  = qb + qi;
        const int cnt = s_cnt[qi];                 // wave-uniform
        if (l == 0) bad[q] = (cnt > CCAP) ? 1 : 0;
        if (cnt > CCAP) continue;                  // ~never: fallback kernel
        if (cnt <= 64) {
            float d = (l < cnt) ? s_cd[qi * CCAP + l] : INFINITY;
            int   i = (l < cnt) ? (int)s_ci[qi * CCAP + l] : 65535;
#pragma unroll
            for (int k = 2; k <= 64; k <<= 1) {
#pragma unroll
                for (int j = k >> 1; j >= 1; j >>= 1) {
                    float pd = __shfl_xor(d, j, 64);
                    int   pi = __shfl_xor(i, j, 64);
                    bool tmn  = (((l & k) == 0) == ((l & j) == 0));
                    bool plt  = (pd < d) || (pd == d && pi < i);
                    bool keep = tmn ? plt : !plt;
                    d = keep ? pd : d;
                    i = keep ? pi : i;
                }
            }
            if (l < KNN) {
                float dt = fmaxf(fmaf(2.0f, d, sqq[s]), 0.0f);
                knn_idx[q * KNN + l] = ebase + i;
                knn_w[q * KNN + l]   = __expf(-10.0f * dt);
            }
        } else {
            for (int p = cnt + l; p < CCAP; p += 64) {
                s_cd[qi * CCAP + p] = INFINITY;
                s_ci[qi * CCAP + p] = (ushort)65535;
            }
#pragma unroll 1
            for (int k = 2; k <= 128; k <<= 1) {
#pragma unroll 1
                for (int j = k >> 1; j >= 1; j >>= 1) {
                    int i0 = ((l & ~(j - 1)) << 1) | (l & (j - 1));
                    int i1 = i0 | j;
                    float dA = s_cd[qi*CCAP + i0], dB = s_cd[qi*CCAP + i1];
                    int   iA = (int)s_ci[qi*CCAP + i0], iB = (int)s_ci[qi*CCAP + i1];
                    bool up = ((i0 & k) == 0);
                    bool sw = up ? ((dB < dA) || (dB == dA && iB < iA))
                                 : ((dA < dB) || (dA == dB && iA < iB));
                    if (sw) {
                        s_cd[qi*CCAP + i0] = dB; s_cd[qi*CCAP + i1] = dA;
                        s_ci[qi*CCAP + i0] = (ushort)iB; s_ci[qi*CCAP + i1] = (ushort)iA;
                    }
                }
            }
            if (l < KNN) {
                float d = s_cd[qi * CCAP + l];
                int   i = (int)s_ci[qi * CCAP + l];
                float dt = fmaxf(fmaf(2.0f, d, sqq[s]), 0.0f);
                knn_idx[q * KNN + l] = ebase + i;
                knn_w[q * KNN + l]   = __expf(-10.0f * dt);
            }
        }
    }
}

// ---------------------------------------------------------------------------
// Kernel 2b: exact fallback for flagged queries (expected never to fire).
// ---------------------------------------------------------------------------
__global__ __launch_bounds__(256) void k_fix(
    const float4* __restrict__ space4, const int* __restrict__ bad,
    int* __restrict__ knn_idx, float* __restrict__ knn_w)
{
    const int q = blockIdx.x * 256 + threadIdx.x;
    if (!bad[q]) return;
    const int eb = (q / M_EV) * M_EV;
    float4 qc = space4[q];
    float sqq = dot4f(qc, qc);
    float ld[KNN]; int li[KNN];
    for (int e = 0; e < KNN; ++e) { ld[e] = INFINITY; li[e] = 0; }
    float cm = INFINITY; int mp = 0;
    for (int c = 0; c < M_EV; ++c) {
        float4 cc = space4[eb + c];
        float d = fmaf(-2.0f, dot4f(qc, cc), sqq + dot4f(cc, cc));
        if (d < cm) {
            ld[mp] = d; li[mp] = c;
            cm = ld[0]; mp = 0;
            for (int e = 1; e < KNN; ++e) if (ld[e] > cm) { cm = ld[e]; mp = e; }
        }
    }
    for (int e = 0; e < KNN; ++e) {
        knn_idx[q * KNN + e] = eb + li[e];
        knn_w[q * KNN + e]   = __expf(-10.0f * fmaxf(ld[e], 0.0f));
    }
}

// ---------------------------------------------------------------------------
// Kernel 3 (fused agg+out), unchanged from round 7.
// ---------------------------------------------------------------------------
#define FSTR 18

__global__ __launch_bounds__(256) void k_tail(
    const float* __restrict__ x, const float* __restrict__ prop,
    const int* __restrict__ knn_idx, const float* __restrict__ knn_w,
    const float* __restrict__ Wo, const float* __restrict__ bo,
    float* __restrict__ out)
{
    __shared__ float fs2[FEAT * FSTR];   // 13824 B
    __shared__ float s_w[48 * 128];      // 24576 B

    const int t = threadIdx.x;
    const int qb = blockIdx.x * 16;

    {
        const int r = t >> 4, c4 = (t & 15) * 4;
        float4 v = *(const float4*)(x + (size_t)(qb + r) * 64 + c4);
        fs2[(c4 + 0) * FSTR + r] = v.x;
        fs2[(c4 + 1) * FSTR + r] = v.y;
        fs2[(c4 + 2) * FSTR + r] = v.z;
        fs2[(c4 + 3) * FSTR + r] = v.w;
    }

    {
        const int p = t & 63;
#pragma unroll 1
        for (int s = 0; s < 4; ++s) {
            const int r = s * 4 + (t >> 6);
            const int q = qb + r;
            float acc = 0.f, mx = -INFINITY;
#pragma unroll 8
            for (int e = 0; e < KNN; ++e) {
                int   ix = knn_idx[q * KNN + e];
                float wv = knn_w[q * KNN + e];
                float g  = wv * prop[(size_t)ix * 64 + p];
                acc += g;
                mx = fmaxf(mx, g);
            }
            fs2[(64 + p) * FSTR + r]  = acc * (1.0f / 32.0f);
            fs2[(128 + p) * FSTR + r] = mx;
        }
    }

    const int rg = t >> 5;
    const int c4 = (t & 31) * 4;
    float acc0[4] = {0.f, 0.f, 0.f, 0.f};
    float acc1[4] = {0.f, 0.f, 0.f, 0.f};

#pragma unroll 1
    for (int cc = 0; cc < 4; ++cc) {
        __syncthreads();
#pragma unroll
        for (int u = 0; u < 6; ++u) {
            int fi = u * 1024 + t * 4;
            *(float4*)(s_w + fi) = *(const float4*)(Wo + (size_t)cc * 48 * 128 + fi);
        }
        __syncthreads();
#pragma unroll 4
        for (int ii = 0; ii < 48; ++ii) {
            int i = cc * 48 + ii;
            float2 f = *(const float2*)(fs2 + i * FSTR + rg * 2);
            float4 wv = *(const float4*)(s_w + ii * 128 + c4);
            acc0[0] = fmaf(f.x, wv.x, acc0[0]); acc0[1] = fmaf(f.x, wv.y, acc0[1]);
            acc0[2] = fmaf(f.x, wv.z, acc0[2]); acc0[3] = fmaf(f.x, wv.w, acc0[3]);
            acc1[0] = fmaf(f.y, wv.x, acc1[0]); acc1[1] = fmaf(f.y, wv.y, acc1[1]);
            acc1[2] = fmaf(f.y, wv.z, acc1[2]); acc1[3] = fmaf(f.y, wv.w, acc1[3]);
        }
    }

    const float4 bc = *(const float4*)(bo + c4);
    float4 o0, o1;
    o0.x = fmaxf(acc0[0] + bc.x, 0.f); o0.y = fmaxf(acc0[1] + bc.y, 0.f);
    o0.z = fmaxf(acc0[2] + bc.z, 0.f); o0.w = fmaxf(acc0[3] + bc.w, 0.f);
    o1.x = fmaxf(acc1[0] + bc.x, 0.f); o1.y = fmaxf(acc1[1] + bc.y, 0.f);
    o1.z = fmaxf(acc1[2] + bc.z, 0.f); o1.w = fmaxf(acc1[3] + bc.w, 0.f);
    *(float4*)(out + (size_t)(qb + rg * 2 + 0) * 128 + c4) = o0;
    *(float4*)(out + (size_t)(qb + rg * 2 + 1) * 128 + c4) = o1;
}

// ---------------------------------------------------------------------------
extern "C" void kernel_launch(void* const* d_in, const int* in_sizes, int n_in,
                              void* d_out, int out_size, void* d_ws, size_t ws_size,
                              hipStream_t stream) {
    const float* x  = (const float*)d_in[0];
    const float* Ws = (const float*)d_in[2];
    const float* bs = (const float*)d_in[3];
    const float* Wp = (const float*)d_in[4];
    const float* bp = (const float*)d_in[5];
    const float* Wo = (const float*)d_in[6];
    const float* bo = (const float*)d_in[7];
    float* out = (float*)d_out;

    float* space = (float*)d_ws;                          // N*4
    float* prop  = space + (size_t)N_TOTAL * 4;           // N*64
    int*   kidx  = (int*)(prop + (size_t)N_TOTAL * 64);   // N*32
    float* kw    = (float*)(kidx + (size_t)N_TOTAL * KNN);// N*32
    int*   bad   = (int*)(kw + (size_t)N_TOTAL * KNN);    // N

    k_linear<<<N_TOTAL / 16, 256, 0, stream>>>(x, Wp, bp, Ws, bs, prop, space);
    k_knn   <<<N_TOTAL / QPB, 256, 0, stream>>>((const float4*)space, kidx, kw, bad);
    k_fix   <<<N_TOTAL / 256, 256, 0, stream>>>((const float4*)space, bad, kidx, kw);
    k_tail  <<<N_TOTAL / 16, 256, 0, stream>>>(x, prop, kidx, kw, Wo, bo, out);
}

// Round 9
// 266.228 us; speedup vs baseline: 1.0877x; 1.0877x over previous
//
#include <hip/hip_runtime.h>
#include <math.h>

#define N_TOTAL 40960
#define M_EV    4096
#define KNN     32
#define FEAT    192   // CIN + 2*PDIM

__device__ __forceinline__ float dot4f(float4 a, float4 b) {
    return fmaf(a.w, b.w, fmaf(a.z, b.z, fmaf(a.y, b.y, a.x * b.x)));
}

// lex-ascending bitonic sort of (d,i) across the 64 lanes of a wave
__device__ __forceinline__ void sort64(float &d, int &i, const int l)
{
#pragma unroll
    for (int k = 2; k <= 64; k <<= 1) {
#pragma unroll
        for (int j = k >> 1; j >= 1; j >>= 1) {
            float pd = __shfl_xor(d, j, 64);
            int   pi = __shfl_xor(i, j, 64);
            bool tmn  = (((l & k) == 0) == ((l & j) == 0));
            bool plt  = (pd < d) || (pd == d && pi < i);
            bool keep = tmn ? plt : !plt;
            d = keep ? pd : d;
            i = keep ? pi : i;
        }
    }
}

// ---------------------------------------------------------------------------
// Kernel 1: space = x@W_space + b_space  [N,4];  prop = x@W_prop + b_prop [N,64]
// ---------------------------------------------------------------------------
__global__ __launch_bounds__(256) void k_linear(
    const float* __restrict__ x,
    const float* __restrict__ Wp, const float* __restrict__ bp,
    const float* __restrict__ Ws, const float* __restrict__ bs,
    float* __restrict__ prop, float* __restrict__ space)
{
    __shared__ float xs[16 * 64];
    const int t = threadIdx.x;
    const int rowbase = blockIdx.x * 16;

    {
        float4 v = *(const float4*)(x + rowbase * 64 + t * 4);
        *(float4*)(xs + t * 4) = v;
    }
    __syncthreads();

    const int j  = t & 63;
    const int rg = t >> 6;
    float a0 = 0.f, a1 = 0.f, a2 = 0.f, a3 = 0.f;
#pragma unroll 8
    for (int c = 0; c < 64; ++c) {
        float w = Wp[c * 64 + j];
        a0 = fmaf(xs[(rg * 4 + 0) * 64 + c], w, a0);
        a1 = fmaf(xs[(rg * 4 + 1) * 64 + c], w, a1);
        a2 = fmaf(xs[(rg * 4 + 2) * 64 + c], w, a2);
        a3 = fmaf(xs[(rg * 4 + 3) * 64 + c], w, a3);
    }
    const float bj = bp[j];
    prop[(rowbase + rg * 4 + 0) * 64 + j] = a0 + bj;
    prop[(rowbase + rg * 4 + 1) * 64 + j] = a1 + bj;
    prop[(rowbase + rg * 4 + 2) * 64 + j] = a2 + bj;
    prop[(rowbase + rg * 4 + 3) * 64 + j] = a3 + bj;

    if (t < 64) {
        const int r = t >> 2, s = t & 3;
        float a = 0.f;
#pragma unroll 8
        for (int c = 0; c < 64; ++c)
            a = fmaf(xs[r * 64 + c], Ws[c * 4 + s], a);
        space[(rowbase + r) * 4 + s] = a + bs[s];
    }
}

// ---------------------------------------------------------------------------
// Kernel 2: exact kNN, threshold-compact-sort (round-7 shape: 512 thr, 4 q/wave)
//  * key dh = 0.5|c|^2 - q.c (monotone with d^2; 5 VALU/(q,c) not 7)
//  * pass 2 compacts INDICES ONLY (no dh store) -> LDS 28.8 KB, 4 blk/CU
//  * select: gather space4[idx], recompute dh with the bitwise-identical
//    chain, register bitonic sorts; cnt<=64 sort, (64,128] sort+merge.
// Guarantee: T = 32nd-smallest of 64 slice-minima => >=32 distinct cands
// with dh<=T => exact top-32 is a subset of the compact set. cnt>=32 always.
// ---------------------------------------------------------------------------
#define QPW   4
#define QPB   32
#define TILEC 1024
#define CCAP  128

__global__ __launch_bounds__(512, 1) void k_knn(
    const float4* __restrict__ space4,
    int* __restrict__ knn_idx, float* __restrict__ knn_w,
    int* __restrict__ bad)
{
    __shared__ float4 s_c[TILEC];         // 16384 B
    __shared__ float  s_h[TILEC];         //  4096 B  (0.5*|c|^2)
    __shared__ ushort s_ci[QPB * CCAP];   //  8192 B
    __shared__ int    s_cnt[QPB];         //   128 B  => 28800 B, 4 blocks/CU

    const int t = threadIdx.x;
    const int w = t >> 6;
    const int l = t & 63;
    const int qb = blockIdx.x * QPB;
    const int ebase = (qb / M_EV) * M_EV;

    if (t < QPB) s_cnt[t] = 0;           // covered by first tile barrier

    float4 qcs[QPW]; float sqq[QPW];
#pragma unroll
    for (int s = 0; s < QPW; ++s) {
        qcs[s] = space4[qb + w * QPW + s];
        sqq[s] = dot4f(qcs[s], qcs[s]);
    }

    float mn[QPW];
#pragma unroll
    for (int s = 0; s < QPW; ++s) mn[s] = INFINITY;

    // ---- pass 1: per-lane slice minima of dh ----
#pragma unroll 1
    for (int tile = 0; tile < M_EV / TILEC; ++tile) {
        __syncthreads();
#pragma unroll
        for (int u = 0; u < TILEC / 512; ++u) {
            int ci = u * 512 + t;
            float4 c = space4[ebase + tile * TILEC + ci];
            s_c[ci] = c;
            s_h[ci] = 0.5f * dot4f(c, c);
        }
        __syncthreads();
#pragma unroll 4
        for (int j = 0; j < TILEC / 64; ++j) {
            int ci = j * 64 + l;
            float4 c = s_c[ci]; float hc = s_h[ci];
#pragma unroll
            for (int s = 0; s < QPW; ++s) {
                float dh = fmaf(-qcs[s].x, c.x, hc);
                dh = fmaf(-qcs[s].y, c.y, dh);
                dh = fmaf(-qcs[s].z, c.z, dh);
                dh = fmaf(-qcs[s].w, c.w, dh);
                mn[s] = fminf(mn[s], dh);
            }
        }
    }

    // ---- T[s] = 32nd smallest of the 64 lane minima ----
    float v[QPW];
#pragma unroll
    for (int s = 0; s < QPW; ++s) v[s] = mn[s];
#pragma unroll
    for (int k = 2; k <= 64; k <<= 1) {
#pragma unroll
        for (int j = k >> 1; j >= 1; j >>= 1) {
            bool tmn = (((l & k) == 0) == ((l & j) == 0));
#pragma unroll
            for (int s = 0; s < QPW; ++s) {
                float p = __shfl_xor(v[s], j, 64);
                v[s] = tmn ? fminf(v[s], p) : fmaxf(v[s], p);
            }
        }
    }
    float T[QPW];
#pragma unroll
    for (int s = 0; s < QPW; ++s) T[s] = __shfl(v[s], 31, 64);

    // ---- pass 2: compact indices with dh<=T (identical fma chain) ----
#pragma unroll 1
    for (int tile = 0; tile < M_EV / TILEC; ++tile) {
        __syncthreads();
#pragma unroll
        for (int u = 0; u < TILEC / 512; ++u) {
            int ci = u * 512 + t;
            float4 c = space4[ebase + tile * TILEC + ci];
            s_c[ci] = c;
            s_h[ci] = 0.5f * dot4f(c, c);
        }
        __syncthreads();
#pragma unroll 2
        for (int j = 0; j < TILEC / 64; ++j) {
            int ci = j * 64 + l;
            float4 c = s_c[ci]; float hc = s_h[ci];
#pragma unroll
            for (int s = 0; s < QPW; ++s) {
                float dh = fmaf(-qcs[s].x, c.x, hc);
                dh = fmaf(-qcs[s].y, c.y, dh);
                dh = fmaf(-qcs[s].z, c.z, dh);
                dh = fmaf(-qcs[s].w, c.w, dh);
                if (dh <= T[s]) {
                    int p = atomicAdd(&s_cnt[w * QPW + s], 1);
                    if (p < CCAP)
                        s_ci[(w * QPW + s) * CCAP + p] = (ushort)(tile * TILEC + ci);
                }
            }
        }
    }
    // own wave wrote its own compact region; DS ops in-order per wave.

    // ---- exact select per query (gather idx, recompute dh, register sort) ----
#pragma unroll 1
    for (int s = 0; s < QPW; ++s) {
        const int qi = w * QPW + s;
        const int q  = qb + qi;
        const int cnt = s_cnt[qi];                 // wave-uniform
        if (l == 0) bad[q] = (cnt > CCAP) ? 1 : 0;
        if (cnt > CCAP) continue;                  // ~never: fallback kernel
        const float4 qc = qcs[s];

        // entry A (lanes 0..63)
        int   iA = (l < cnt) ? (int)s_ci[qi * CCAP + l] : 65535;
        float dA;
        {
            float4 c = space4[ebase + ((l < cnt) ? iA : 0)];
            float hc = 0.5f * dot4f(c, c);
            float dh = fmaf(-qc.x, c.x, hc);
            dh = fmaf(-qc.y, c.y, dh);
            dh = fmaf(-qc.z, c.z, dh);
            dh = fmaf(-qc.w, c.w, dh);
            dA = (l < cnt) ? dh : INFINITY;
        }

        float d; int i;
        if (cnt <= 64) {
            d = dA; i = iA;
            sort64(d, i, l);
        } else {
            // entry B (lanes 64..127)
            int   iB = (64 + l < cnt) ? (int)s_ci[qi * CCAP + 64 + l] : 65535;
            float dB;
            {
                float4 c = space4[ebase + ((64 + l < cnt) ? iB : 0)];
                float hc = 0.5f * dot4f(c, c);
                float dh = fmaf(-qc.x, c.x, hc);
                dh = fmaf(-qc.y, c.y, dh);
                dh = fmaf(-qc.z, c.z, dh);
                dh = fmaf(-qc.w, c.w, dh);
                dB = (64 + l < cnt) ? dh : INFINITY;
            }
            sort64(dA, iA, l);
            sort64(dB, iB, l);
            // Batcher merge: concat(A, rev(B)) bitonic; lower half = lex-min
            float dBr = __shfl(dB, 63 - l, 64);
            int   iBr = __shfl(iB, 63 - l, 64);
            bool bl = (dBr < dA) || (dBr == dA && iBr < iA);
            d = bl ? dBr : dA;
            i = bl ? iBr : iA;
            // clean the bitonic lower half -> ascending
#pragma unroll
            for (int j = 32; j >= 1; j >>= 1) {
                float pd = __shfl_xor(d, j, 64);
                int   pi = __shfl_xor(i, j, 64);
                bool plt  = (pd < d) || (pd == d && pi < i);
                bool keep = ((l & j) == 0) ? plt : !plt;
                d = keep ? pd : d;
                i = keep ? pi : i;
            }
        }

        if (l < KNN) {
            float dt = fmaxf(fmaf(2.0f, d, sqq[s]), 0.0f);
            knn_idx[q * KNN + l] = ebase + i;
            knn_w[q * KNN + l]   = __expf(-10.0f * dt);
        }
    }
}

// ---------------------------------------------------------------------------
// Kernel 2b: exact fallback for flagged queries (expected never to fire).
// ---------------------------------------------------------------------------
__global__ __launch_bounds__(256) void k_fix(
    const float4* __restrict__ space4, const int* __restrict__ bad,
    int* __restrict__ knn_idx, float* __restrict__ knn_w)
{
    const int q = blockIdx.x * 256 + threadIdx.x;
    if (!bad[q]) return;
    const int eb = (q / M_EV) * M_EV;
    float4 qc = space4[q];
    float sqq = dot4f(qc, qc);
    float ld[KNN]; int li[KNN];
    for (int e = 0; e < KNN; ++e) { ld[e] = INFINITY; li[e] = 0; }
    float cm = INFINITY; int mp = 0;
    for (int c = 0; c < M_EV; ++c) {
        float4 cc = space4[eb + c];
        float d = fmaf(-2.0f, dot4f(qc, cc), sqq + dot4f(cc, cc));
        if (d < cm) {
            ld[mp] = d; li[mp] = c;
            cm = ld[0]; mp = 0;
            for (int e = 1; e < KNN; ++e) if (ld[e] > cm) { cm = ld[e]; mp = e; }
        }
    }
    for (int e = 0; e < KNN; ++e) {
        knn_idx[q * KNN + e] = eb + li[e];
        knn_w[q * KNN + e]   = __expf(-10.0f * fmaxf(ld[e], 0.0f));
    }
}

// ---------------------------------------------------------------------------
// Kernel 3 (fused agg+out), unchanged from round 7.
// ---------------------------------------------------------------------------
#define FSTR 18

__global__ __launch_bounds__(256) void k_tail(
    const float* __restrict__ x, const float* __restrict__ prop,
    const int* __restrict__ knn_idx, const float* __restrict__ knn_w,
    const float* __restrict__ Wo, const float* __restrict__ bo,
    float* __restrict__ out)
{
    __shared__ float fs2[FEAT * FSTR];   // 13824 B
    __shared__ float s_w[48 * 128];      // 24576 B

    const int t = threadIdx.x;
    const int qb = blockIdx.x * 16;

    {
        const int r = t >> 4, c4 = (t & 15) * 4;
        float4 v = *(const float4*)(x + (size_t)(qb + r) * 64 + c4);
        fs2[(c4 + 0) * FSTR + r] = v.x;
        fs2[(c4 + 1) * FSTR + r] = v.y;
        fs2[(c4 + 2) * FSTR + r] = v.z;
        fs2[(c4 + 3) * FSTR + r] = v.w;
    }

    {
        const int p = t & 63;
#pragma unroll 1
        for (int s = 0; s < 4; ++s) {
            const int r = s * 4 + (t >> 6);
            const int q = qb + r;
            float acc = 0.f, mx = -INFINITY;
#pragma unroll 8
            for (int e = 0; e < KNN; ++e) {
                int   ix = knn_idx[q * KNN + e];
                float wv = knn_w[q * KNN + e];
                float g  = wv * prop[(size_t)ix * 64 + p];
                acc += g;
                mx = fmaxf(mx, g);
            }
            fs2[(64 + p) * FSTR + r]  = acc * (1.0f / 32.0f);
            fs2[(128 + p) * FSTR + r] = mx;
        }
    }

    const int rg = t >> 5;
    const int c4 = (t & 31) * 4;
    float acc0[4] = {0.f, 0.f, 0.f, 0.f};
    float acc1[4] = {0.f, 0.f, 0.f, 0.f};

#pragma unroll 1
    for (int cc = 0; cc < 4; ++cc) {
        __syncthreads();
#pragma unroll
        for (int u = 0; u < 6; ++u) {
            int fi = u * 1024 + t * 4;
            *(float4*)(s_w + fi) = *(const float4*)(Wo + (size_t)cc * 48 * 128 + fi);
        }
        __syncthreads();
#pragma unroll 4
        for (int ii = 0; ii < 48; ++ii) {
            int i = cc * 48 + ii;
            float2 f = *(const float2*)(fs2 + i * FSTR + rg * 2);
            float4 wv = *(const float4*)(s_w + ii * 128 + c4);
            acc0[0] = fmaf(f.x, wv.x, acc0[0]); acc0[1] = fmaf(f.x, wv.y, acc0[1]);
            acc0[2] = fmaf(f.x, wv.z, acc0[2]); acc0[3] = fmaf(f.x, wv.w, acc0[3]);
            acc1[0] = fmaf(f.y, wv.x, acc1[0]); acc1[1] = fmaf(f.y, wv.y, acc1[1]);
            acc1[2] = fmaf(f.y, wv.z, acc1[2]); acc1[3] = fmaf(f.y, wv.w, acc1[3]);
        }
    }

    const float4 bc = *(const float4*)(bo + c4);
    float4 o0, o1;
    o0.x = fmaxf(acc0[0] + bc.x, 0.f); o0.y = fmaxf(acc0[1] + bc.y, 0.f);
    o0.z = fmaxf(acc0[2] + bc.z, 0.f); o0.w = fmaxf(acc0[3] + bc.w, 0.f);
    o1.x = fmaxf(acc1[0] + bc.x, 0.f); o1.y = fmaxf(acc1[1] + bc.y, 0.f);
    o1.z = fmaxf(acc1[2] + bc.z, 0.f); o1.w = fmaxf(acc1[3] + bc.w, 0.f);
    *(float4*)(out + (size_t)(qb + rg * 2 + 0) * 128 + c4) = o0;
    *(float4*)(out + (size_t)(qb + rg * 2 + 1) * 128 + c4) = o1;
}

// ---------------------------------------------------------------------------
extern "C" void kernel_launch(void* const* d_in, const int* in_sizes, int n_in,
                              void* d_out, int out_size, void* d_ws, size_t ws_size,
                              hipStream_t stream) {
    const float* x  = (const float*)d_in[0];
    const float* Ws = (const float*)d_in[2];
    const float* bs = (const float*)d_in[3];
    const float* Wp = (const float*)d_in[4];
    const float* bp = (const float*)d_in[5];
    const float* Wo = (const float*)d_in[6];
    const float* bo = (const float*)d_in[7];
    float* out = (float*)d_out;

    float* space = (float*)d_ws;                          // N*4
    float* prop  = space + (size_t)N_TOTAL * 4;           // N*64
    int*   kidx  = (int*)(prop + (size_t)N_TOTAL * 64);   // N*32
    float* kw    = (float*)(kidx + (size_t)N_TOTAL * KNN);// N*32
    int*   bad   = (int*)(kw + (size_t)N_TOTAL * KNN);    // N

    k_linear<<<N_TOTAL / 16, 256, 0, stream>>>(x, Wp, bp, Ws, bs, prop, space);
    k_knn   <<<N_TOTAL / QPB, 512, 0, stream>>>((const float4*)space, kidx, kw, bad);
    k_fix   <<<N_TOTAL / 256, 256, 0, stream>>>((const float4*)space, bad, kidx, kw);
    k_tail  <<<N_TOTAL / 16, 256, 0, stream>>>(x, prop, kidx, kw, Wo, bo, out);
}

// Round 10
// 234.939 us; speedup vs baseline: 1.2326x; 1.1332x over previous
//
#include <hip/hip_runtime.h>
#include <math.h>

#define N_TOTAL 40960
#define M_EV    4096
#define KNN     32
#define FEAT    192   // CIN + 2*PDIM

__device__ __forceinline__ float dot4f(float4 a, float4 b) {
    return fmaf(a.w, b.w, fmaf(a.z, b.z, fmaf(a.y, b.y, a.x * b.x)));
}

// lex-ascending bitonic sort of (d,i) across the 64 lanes of a wave
__device__ __forceinline__ void sort64(float &d, int &i, const int l)
{
#pragma unroll
    for (int k = 2; k <= 64; k <<= 1) {
#pragma unroll
        for (int j = k >> 1; j >= 1; j >>= 1) {
            float pd = __shfl_xor(d, j, 64);
            int   pi = __shfl_xor(i, j, 64);
            bool tmn  = (((l & k) == 0) == ((l & j) == 0));
            bool plt  = (pd < d) || (pd == d && pi < i);
            bool keep = tmn ? plt : !plt;
            d = keep ? pd : d;
            i = keep ? pi : i;
        }
    }
}

// ---------------------------------------------------------------------------
// Kernel 1: space = x@W_space + b_space  [N,4];  prop = x@W_prop + b_prop [N,64]
// ---------------------------------------------------------------------------
__global__ __launch_bounds__(256) void k_linear(
    const float* __restrict__ x,
    const float* __restrict__ Wp, const float* __restrict__ bp,
    const float* __restrict__ Ws, const float* __restrict__ bs,
    float* __restrict__ prop, float* __restrict__ space)
{
    __shared__ float xs[16 * 64];
    const int t = threadIdx.x;
    const int rowbase = blockIdx.x * 16;

    {
        float4 v = *(const float4*)(x + rowbase * 64 + t * 4);
        *(float4*)(xs + t * 4) = v;
    }
    __syncthreads();

    const int j  = t & 63;
    const int rg = t >> 6;
    float a0 = 0.f, a1 = 0.f, a2 = 0.f, a3 = 0.f;
#pragma unroll 8
    for (int c = 0; c < 64; ++c) {
        float w = Wp[c * 64 + j];
        a0 = fmaf(xs[(rg * 4 + 0) * 64 + c], w, a0);
        a1 = fmaf(xs[(rg * 4 + 1) * 64 + c], w, a1);
        a2 = fmaf(xs[(rg * 4 + 2) * 64 + c], w, a2);
        a3 = fmaf(xs[(rg * 4 + 3) * 64 + c], w, a3);
    }
    const float bj = bp[j];
    prop[(rowbase + rg * 4 + 0) * 64 + j] = a0 + bj;
    prop[(rowbase + rg * 4 + 1) * 64 + j] = a1 + bj;
    prop[(rowbase + rg * 4 + 2) * 64 + j] = a2 + bj;
    prop[(rowbase + rg * 4 + 3) * 64 + j] = a3 + bj;

    if (t < 64) {
        const int r = t >> 2, s = t & 3;
        float a = 0.f;
#pragma unroll 8
        for (int c = 0; c < 64; ++c)
            a = fmaf(xs[r * 64 + c], Ws[c * 4 + s], a);
        space[(rowbase + r) * 4 + s] = a + bs[s];
    }
}

// ---------------------------------------------------------------------------
// Kernel 2: exact kNN, threshold-compact-sort (512 thr, 4 q/wave).
//  * key dh = 0.5|c|^2 - q.c (monotone with d^2)
//  * pass 2 compacts INDICES ONLY -> LDS 28.8 KB
//  * select: gather space4[idx], recompute dh (bitwise-identical chain),
//    register bitonic sorts. SELECT LOOP FULLY UNROLLED: round 9 left it
//    #pragma unroll 1, so qcs[s] was runtime-indexed -> alloca -> scratch
//    (FETCH 19.6 MB / WRITE 51.4 MB spill signature, 125 us). Constant
//    indices keep qcs/sqq/T in registers.
// ---------------------------------------------------------------------------
#define QPW   4
#define QPB   32
#define TILEC 1024
#define CCAP  128

__global__ __launch_bounds__(512, 1) void k_knn(
    const float4* __restrict__ space4,
    int* __restrict__ knn_idx, float* __restrict__ knn_w,
    int* __restrict__ bad)
{
    __shared__ float4 s_c[TILEC];         // 16384 B
    __shared__ float  s_h[TILEC];         //  4096 B  (0.5*|c|^2)
    __shared__ ushort s_ci[QPB * CCAP];   //  8192 B
    __shared__ int    s_cnt[QPB];         //   128 B  => 28800 B

    const int t = threadIdx.x;
    const int w = t >> 6;
    const int l = t & 63;
    const int qb = blockIdx.x * QPB;
    const int ebase = (qb / M_EV) * M_EV;

    if (t < QPB) s_cnt[t] = 0;           // covered by first tile barrier

    float4 qcs[QPW]; float sqq[QPW];
#pragma unroll
    for (int s = 0; s < QPW; ++s) {
        qcs[s] = space4[qb + w * QPW + s];
        sqq[s] = dot4f(qcs[s], qcs[s]);
    }

    float mn[QPW];
#pragma unroll
    for (int s = 0; s < QPW; ++s) mn[s] = INFINITY;

    // ---- pass 1: per-lane slice minima of dh ----
#pragma unroll 1
    for (int tile = 0; tile < M_EV / TILEC; ++tile) {
        __syncthreads();
#pragma unroll
        for (int u = 0; u < TILEC / 512; ++u) {
            int ci = u * 512 + t;
            float4 c = space4[ebase + tile * TILEC + ci];
            s_c[ci] = c;
            s_h[ci] = 0.5f * dot4f(c, c);
        }
        __syncthreads();
#pragma unroll 4
        for (int j = 0; j < TILEC / 64; ++j) {
            int ci = j * 64 + l;
            float4 c = s_c[ci]; float hc = s_h[ci];
#pragma unroll
            for (int s = 0; s < QPW; ++s) {
                float dh = fmaf(-qcs[s].x, c.x, hc);
                dh = fmaf(-qcs[s].y, c.y, dh);
                dh = fmaf(-qcs[s].z, c.z, dh);
                dh = fmaf(-qcs[s].w, c.w, dh);
                mn[s] = fminf(mn[s], dh);
            }
        }
    }

    // ---- T[s] = 32nd smallest of the 64 lane minima ----
    float v[QPW];
#pragma unroll
    for (int s = 0; s < QPW; ++s) v[s] = mn[s];
#pragma unroll
    for (int k = 2; k <= 64; k <<= 1) {
#pragma unroll
        for (int j = k >> 1; j >= 1; j >>= 1) {
            bool tmn = (((l & k) == 0) == ((l & j) == 0));
#pragma unroll
            for (int s = 0; s < QPW; ++s) {
                float p = __shfl_xor(v[s], j, 64);
                v[s] = tmn ? fminf(v[s], p) : fmaxf(v[s], p);
            }
        }
    }
    float T[QPW];
#pragma unroll
    for (int s = 0; s < QPW; ++s) T[s] = __shfl(v[s], 31, 64);

    // ---- pass 2: compact indices with dh<=T (identical fma chain) ----
#pragma unroll 1
    for (int tile = 0; tile < M_EV / TILEC; ++tile) {
        __syncthreads();
#pragma unroll
        for (int u = 0; u < TILEC / 512; ++u) {
            int ci = u * 512 + t;
            float4 c = space4[ebase + tile * TILEC + ci];
            s_c[ci] = c;
            s_h[ci] = 0.5f * dot4f(c, c);
        }
        __syncthreads();
#pragma unroll 2
        for (int j = 0; j < TILEC / 64; ++j) {
            int ci = j * 64 + l;
            float4 c = s_c[ci]; float hc = s_h[ci];
#pragma unroll
            for (int s = 0; s < QPW; ++s) {
                float dh = fmaf(-qcs[s].x, c.x, hc);
                dh = fmaf(-qcs[s].y, c.y, dh);
                dh = fmaf(-qcs[s].z, c.z, dh);
                dh = fmaf(-qcs[s].w, c.w, dh);
                if (dh <= T[s]) {
                    int p = atomicAdd(&s_cnt[w * QPW + s], 1);
                    if (p < CCAP)
                        s_ci[(w * QPW + s) * CCAP + p] = (ushort)(tile * TILEC + ci);
                }
            }
        }
    }
    // own wave wrote its own compact region; DS ops in-order per wave.

    // ---- exact select per query (FULLY UNROLLED: constant s everywhere) ----
#pragma unroll
    for (int s = 0; s < QPW; ++s) {
        const int qi = w * QPW + s;
        const int q  = qb + qi;
        const int cnt = s_cnt[qi];                 // wave-uniform
        if (l == 0) bad[q] = (cnt > CCAP) ? 1 : 0;
        if (cnt <= CCAP) {
            const float4 qc = qcs[s];

            // entry A (lanes 0..63)
            int   iA = (l < cnt) ? (int)s_ci[qi * CCAP + l] : 65535;
            float dA;
            {
                float4 c = space4[ebase + ((l < cnt) ? iA : 0)];
                float hc = 0.5f * dot4f(c, c);
                float dh = fmaf(-qc.x, c.x, hc);
                dh = fmaf(-qc.y, c.y, dh);
                dh = fmaf(-qc.z, c.z, dh);
                dh = fmaf(-qc.w, c.w, dh);
                dA = (l < cnt) ? dh : INFINITY;
            }

            float d; int i;
            if (cnt <= 64) {
                d = dA; i = iA;
                sort64(d, i, l);
            } else {
                // entry B (lanes 64..127)
                int   iB = (64 + l < cnt) ? (int)s_ci[qi * CCAP + 64 + l] : 65535;
                float dB;
                {
                    float4 c = space4[ebase + ((64 + l < cnt) ? iB : 0)];
                    float hc = 0.5f * dot4f(c, c);
                    float dh = fmaf(-qc.x, c.x, hc);
                    dh = fmaf(-qc.y, c.y, dh);
                    dh = fmaf(-qc.z, c.z, dh);
                    dh = fmaf(-qc.w, c.w, dh);
                    dB = (64 + l < cnt) ? dh : INFINITY;
                }
                sort64(dA, iA, l);
                sort64(dB, iB, l);
                // Batcher merge: concat(A, rev(B)) bitonic; lower half = lex-min
                float dBr = __shfl(dB, 63 - l, 64);
                int   iBr = __shfl(iB, 63 - l, 64);
                bool bl = (dBr < dA) || (dBr == dA && iBr < iA);
                d = bl ? dBr : dA;
                i = bl ? iBr : iA;
                // clean the bitonic lower half -> ascending
#pragma unroll
                for (int j = 32; j >= 1; j >>= 1) {
                    float pd = __shfl_xor(d, j, 64);
                    int   pi = __shfl_xor(i, j, 64);
                    bool plt  = (pd < d) || (pd == d && pi < i);
                    bool keep = ((l & j) == 0) ? plt : !plt;
                    d = keep ? pd : d;
                    i = keep ? pi : i;
                }
            }

            if (l < KNN) {
                float dt = fmaxf(fmaf(2.0f, d, sqq[s]), 0.0f);
                knn_idx[q * KNN + l] = ebase + i;
                knn_w[q * KNN + l]   = __expf(-10.0f * dt);
            }
        }
    }
}

// ---------------------------------------------------------------------------
// Kernel 2b: exact fallback for flagged queries (expected never to fire).
// ---------------------------------------------------------------------------
__global__ __launch_bounds__(256) void k_fix(
    const float4* __restrict__ space4, const int* __restrict__ bad,
    int* __restrict__ knn_idx, float* __restrict__ knn_w)
{
    const int q = blockIdx.x * 256 + threadIdx.x;
    if (!bad[q]) return;
    const int eb = (q / M_EV) * M_EV;
    float4 qc = space4[q];
    float sqq = dot4f(qc, qc);
    float ld[KNN]; int li[KNN];
    for (int e = 0; e < KNN; ++e) { ld[e] = INFINITY; li[e] = 0; }
    float cm = INFINITY; int mp = 0;
    for (int c = 0; c < M_EV; ++c) {
        float4 cc = space4[eb + c];
        float d = fmaf(-2.0f, dot4f(qc, cc), sqq + dot4f(cc, cc));
        if (d < cm) {
            ld[mp] = d; li[mp] = c;
            cm = ld[0]; mp = 0;
            for (int e = 1; e < KNN; ++e) if (ld[e] > cm) { cm = ld[e]; mp = e; }
        }
    }
    for (int e = 0; e < KNN; ++e) {
        knn_idx[q * KNN + e] = eb + li[e];
        knn_w[q * KNN + e]   = __expf(-10.0f * fmaxf(ld[e], 0.0f));
    }
}

// ---------------------------------------------------------------------------
// Kernel 3 (fused agg+out), unchanged.
// ---------------------------------------------------------------------------
#define FSTR 18

__global__ __launch_bounds__(256) void k_tail(
    const float* __restrict__ x, const float* __restrict__ prop,
    const int* __restrict__ knn_idx, const float* __restrict__ knn_w,
    const float* __restrict__ Wo, const float* __restrict__ bo,
    float* __restrict__ out)
{
    __shared__ float fs2[FEAT * FSTR];   // 13824 B
    __shared__ float s_w[48 * 128];      // 24576 B

    const int t = threadIdx.x;
    const int qb = blockIdx.x * 16;

    {
        const int r = t >> 4, c4 = (t & 15) * 4;
        float4 v = *(const float4*)(x + (size_t)(qb + r) * 64 + c4);
        fs2[(c4 + 0) * FSTR + r] = v.x;
        fs2[(c4 + 1) * FSTR + r] = v.y;
        fs2[(c4 + 2) * FSTR + r] = v.z;
        fs2[(c4 + 3) * FSTR + r] = v.w;
    }

    {
        const int p = t & 63;
#pragma unroll 1
        for (int s = 0; s < 4; ++s) {
            const int r = s * 4 + (t >> 6);
            const int q = qb + r;
            float acc = 0.f, mx = -INFINITY;
#pragma unroll 8
            for (int e = 0; e < KNN; ++e) {
                int   ix = knn_idx[q * KNN + e];
                float wv = knn_w[q * KNN + e];
                float g  = wv * prop[(size_t)ix * 64 + p];
                acc += g;
                mx = fmaxf(mx, g);
            }
            fs2[(64 + p) * FSTR + r]  = acc * (1.0f / 32.0f);
            fs2[(128 + p) * FSTR + r] = mx;
        }
    }

    const int rg = t >> 5;
    const int c4 = (t & 31) * 4;
    float acc0[4] = {0.f, 0.f, 0.f, 0.f};
    float acc1[4] = {0.f, 0.f, 0.f, 0.f};

#pragma unroll 1
    for (int cc = 0; cc < 4; ++cc) {
        __syncthreads();
#pragma unroll
        for (int u = 0; u < 6; ++u) {
            int fi = u * 1024 + t * 4;
            *(float4*)(s_w + fi) = *(const float4*)(Wo + (size_t)cc * 48 * 128 + fi);
        }
        __syncthreads();
#pragma unroll 4
        for (int ii = 0; ii < 48; ++ii) {
            int i = cc * 48 + ii;
            float2 f = *(const float2*)(fs2 + i * FSTR + rg * 2);
            float4 wv = *(const float4*)(s_w + ii * 128 + c4);
            acc0[0] = fmaf(f.x, wv.x, acc0[0]); acc0[1] = fmaf(f.x, wv.y, acc0[1]);
            acc0[2] = fmaf(f.x, wv.z, acc0[2]); acc0[3] = fmaf(f.x, wv.w, acc0[3]);
            acc1[0] = fmaf(f.y, wv.x, acc1[0]); acc1[1] = fmaf(f.y, wv.y, acc1[1]);
            acc1[2] = fmaf(f.y, wv.z, acc1[2]); acc1[3] = fmaf(f.y, wv.w, acc1[3]);
        }
    }

    const float4 bc = *(const float4*)(bo + c4);
    float4 o0, o1;
    o0.x = fmaxf(acc0[0] + bc.x, 0.f); o0.y = fmaxf(acc0[1] + bc.y, 0.f);
    o0.z = fmaxf(acc0[2] + bc.z, 0.f); o0.w = fmaxf(acc0[3] + bc.w, 0.f);
    o1.x = fmaxf(acc1[0] + bc.x, 0.f); o1.y = fmaxf(acc1[1] + bc.y, 0.f);
    o1.z = fmaxf(acc1[2] + bc.z, 0.f); o1.w = fmaxf(acc1[3] + bc.w, 0.f);
    *(float4*)(out + (size_t)(qb + rg * 2 + 0) * 128 + c4) = o0;
    *(float4*)(out + (size_t)(qb + rg * 2 + 1) * 128 + c4) = o1;
}

// ---------------------------------------------------------------------------
extern "C" void kernel_launch(void* const* d_in, const int* in_sizes, int n_in,
                              void* d_out, int out_size, void* d_ws, size_t ws_size,
                              hipStream_t stream) {
    const float* x  = (const float*)d_in[0];
    const float* Ws = (const float*)d_in[2];
    const float* bs = (const float*)d_in[3];
    const float* Wp = (const float*)d_in[4];
    const float* bp = (const float*)d_in[5];
    const float* Wo = (const float*)d_in[6];
    const float* bo = (const float*)d_in[7];
    float* out = (float*)d_out;

    float* space = (float*)d_ws;                          // N*4
    float* prop  = space + (size_t)N_TOTAL * 4;           // N*64
    int*   kidx  = (int*)(prop + (size_t)N_TOTAL * 64);   // N*32
    float* kw    = (float*)(kidx + (size_t)N_TOTAL * KNN);// N*32
    int*   bad   = (int*)(kw + (size_t)N_TOTAL * KNN);    // N

    k_linear<<<N_TOTAL / 16, 256, 0, stream>>>(x, Wp, bp, Ws, bs, prop, space);
    k_knn   <<<N_TOTAL / QPB, 512, 0, stream>>>((const float4*)space, kidx, kw, bad);
    k_fix   <<<N_TOTAL / 256, 256, 0, stream>>>((const float4*)space, bad, kidx, kw);
    k_tail  <<<N_TOTAL / 16, 256, 0, stream>>>(x, prop, kidx, kw, Wo, bo, out);
}